// Round 1
// baseline (440.076 us; speedup 1.0000x reference)
//
#include <hip/hip_runtime.h>
#include <hip/hip_bf16.h>

#define D 128          // feature dim (D_IN == D_H == 128)
#define GBM 64         // GEMM row tile
#define GBK 32         // GEMM k tile
#define SA_STRIDE 36   // padded k-stride for A tile (float4-aligned, conflict-free)

// ---------------- CSR build ----------------

__global__ void hist_kernel(const int* __restrict__ col, int* __restrict__ cnt, int E) {
    int i = blockIdx.x * 256 + threadIdx.x;
    if (i < E) atomicAdd(&cnt[col[i]], 1);
}

// single-block exclusive scan over n counts -> ptr[0..n]
__global__ __launch_bounds__(1024) void scan_kernel(const int* __restrict__ cnt,
                                                    int* __restrict__ ptr, int n) {
    __shared__ int wsum[16];
    __shared__ int carry;
    const int tid  = threadIdx.x;
    const int lane = tid & 63;
    const int wid  = tid >> 6;
    if (tid == 0) carry = 0;
    __syncthreads();
    for (int base = 0; base < n; base += 1024) {
        const int i = base + tid;
        int v = (i < n) ? cnt[i] : 0;
        int x = v;
        #pragma unroll
        for (int off = 1; off < 64; off <<= 1) {
            int y = __shfl_up(x, off, 64);
            if (lane >= off) x += y;
        }
        if (lane == 63) wsum[wid] = x;
        __syncthreads();
        if (tid < 16) {
            int s = wsum[tid];
            #pragma unroll
            for (int off = 1; off < 16; off <<= 1) {
                int y = __shfl_up(s, off, 64);
                if (tid >= off) s += y;
            }
            wsum[tid] = s;
        }
        __syncthreads();
        int prefix = carry + (wid ? wsum[wid - 1] : 0);
        if (i < n) ptr[i] = prefix + x - v;   // exclusive
        __syncthreads();                      // everyone done reading carry/wsum
        if (tid == 0) carry += wsum[15];
        __syncthreads();                      // carry updated before next chunk
    }
    if (tid == 0) ptr[n] = carry;
}

__global__ void dis_kernel(const int* __restrict__ cnt, float* __restrict__ dis, int n) {
    int i = blockIdx.x * 256 + threadIdx.x;
    if (i < n) dis[i] = rsqrtf((float)(cnt[i] + 1));   // +1 = self-loop
}

__global__ void scatter_kernel(const int* __restrict__ row, const int* __restrict__ col,
                               const int* __restrict__ ptr, int* __restrict__ fill,
                               int* __restrict__ ssrc, int E) {
    int i = blockIdx.x * 256 + threadIdx.x;
    if (i < E) {
        int d = col[i];
        int p = ptr[d] + atomicAdd(&fill[d], 1);
        ssrc[p] = row[i];
    }
}

// ---------------- GEMM: C[M,128] = A[M,128] @ W[128,128], fp32 ----------------

__global__ __launch_bounds__(256) void gemm128(const float* __restrict__ A,
                                               const float* __restrict__ Wm,
                                               float* __restrict__ C, int M) {
    __shared__ float sA[GBM * SA_STRIDE];   // 9216 B
    __shared__ float sW[GBK * D];           // 16384 B
    const int tid  = threadIdx.x;
    const int row0 = blockIdx.x * GBM;
    const int tc   = (tid & 15) * 8;        // col start (8 cols)
    const int tr   = (tid >> 4) * 4;        // row start (4 rows)

    float acc[4][8];
    #pragma unroll
    for (int r = 0; r < 4; ++r)
        #pragma unroll
        for (int c = 0; c < 8; ++c) acc[r][c] = 0.f;

    const int lr = tid >> 3;          // A-load row   0..31
    const int lk = (tid & 7) * 4;     // A-load k     0..28
    const int wr = tid >> 5;          // W-load k     0..7
    const int wc = (tid & 31) * 4;    // W-load col   0..124

    for (int k0 = 0; k0 < D; k0 += GBK) {
        #pragma unroll
        for (int rr = 0; rr < GBM; rr += 32) {
            int r = lr + rr;
            int grow = row0 + r;
            if (grow >= M) grow = M - 1;
            *(float4*)&sA[r * SA_STRIDE + lk] = *(const float4*)&A[grow * D + k0 + lk];
        }
        #pragma unroll
        for (int kk = 0; kk < GBK; kk += 8) {
            int k = wr + kk;
            *(float4*)&sW[k * D + wc] = *(const float4*)&Wm[(k0 + k) * D + wc];
        }
        __syncthreads();
        #pragma unroll
        for (int k = 0; k < GBK; k += 4) {
            float4 a[4];
            #pragma unroll
            for (int r = 0; r < 4; ++r)
                a[r] = *(float4*)&sA[(tr + r) * SA_STRIDE + k];
            #pragma unroll
            for (int kk = 0; kk < 4; ++kk) {
                float4 w0 = *(float4*)&sW[(k + kk) * D + tc];
                float4 w1 = *(float4*)&sW[(k + kk) * D + tc + 4];
                #pragma unroll
                for (int r = 0; r < 4; ++r) {
                    float av = (kk == 0) ? a[r].x : (kk == 1) ? a[r].y
                             : (kk == 2) ? a[r].z : a[r].w;
                    acc[r][0] += av * w0.x; acc[r][1] += av * w0.y;
                    acc[r][2] += av * w0.z; acc[r][3] += av * w0.w;
                    acc[r][4] += av * w1.x; acc[r][5] += av * w1.y;
                    acc[r][6] += av * w1.z; acc[r][7] += av * w1.w;
                }
            }
        }
        __syncthreads();
    }
    #pragma unroll
    for (int r = 0; r < 4; ++r) {
        int grow = row0 + tr + r;
        if (grow < M) {
            float4 o0 = {acc[r][0], acc[r][1], acc[r][2], acc[r][3]};
            float4 o1 = {acc[r][4], acc[r][5], acc[r][6], acc[r][7]};
            *(float4*)&C[grow * D + tc]     = o0;
            *(float4*)&C[grow * D + tc + 4] = o1;
        }
    }
}

// ---------------- Aggregation: one wave per node ----------------
// out[v] = relu( dis[v]^2 * H[v] + sum_e dis[src]*dis[v] * H[src] + b )

__global__ __launch_bounds__(256) void agg_kernel(const float* __restrict__ H,
                                                  const int* __restrict__ ptr,
                                                  const int* __restrict__ ssrc,
                                                  const float* __restrict__ dis,
                                                  const float* __restrict__ bias,
                                                  float* __restrict__ out, int n) {
    const int gw   = (blockIdx.x * 256 + threadIdx.x) >> 6;  // global wave = node
    const int lane = threadIdx.x & 63;
    if (gw >= n) return;
    const int v = gw;
    const float dv = dis[v];
    const int fo = lane * 2;

    float2 hv = *(const float2*)&H[v * D + fo];
    float ws = dv * dv;
    float ax = ws * hv.x, ay = ws * hv.y;

    const int e0 = ptr[v], e1 = ptr[v + 1];
    int e = e0;
    for (; e + 1 < e1; e += 2) {
        int s0 = ssrc[e];
        int s1 = ssrc[e + 1];
        float w0 = dis[s0] * dv;
        float w1 = dis[s1] * dv;
        float2 h0 = *(const float2*)&H[s0 * D + fo];
        float2 h1 = *(const float2*)&H[s1 * D + fo];
        ax += w0 * h0.x + w1 * h1.x;
        ay += w0 * h0.y + w1 * h1.y;
    }
    if (e < e1) {
        int s0 = ssrc[e];
        float w0 = dis[s0] * dv;
        float2 h0 = *(const float2*)&H[s0 * D + fo];
        ax += w0 * h0.x;
        ay += w0 * h0.y;
    }
    float2 bb = *(const float2*)&bias[fo];
    float2 res;
    res.x = fmaxf(ax + bb.x, 0.f);
    res.y = fmaxf(ay + bb.y, 0.f);
    *(float2*)&out[v * D + fo] = res;
}

// ---------------- launch ----------------

extern "C" void kernel_launch(void* const* d_in, const int* in_sizes, int n_in,
                              void* d_out, int out_size, void* d_ws, size_t ws_size,
                              hipStream_t stream) {
    const float* x  = (const float*)d_in[0];
    const int*   ei = (const int*)d_in[1];
    const float* W0 = (const float*)d_in[2];
    const float* b0 = (const float*)d_in[3];
    const float* W1 = (const float*)d_in[4];
    const float* b1 = (const float*)d_in[5];
    const float* W2 = (const float*)d_in[6];
    const float* b2 = (const float*)d_in[7];
    float* out = (float*)d_out;

    const int n = in_sizes[0] / D;     // 50000
    const int E = in_sizes[1] / 2;     // 640000
    const int* row = ei;
    const int* col = ei + E;

    char* w = (char*)d_ws;
    float* hbuf = (float*)w;
    size_t o = (size_t)n * D * 4;
    int* cnt  = (int*)(w + o); o += (size_t)n * 4;
    int* fill = (int*)(w + o); o += (size_t)n * 4;      // adjacent to cnt -> one memset
    int* ptrv = (int*)(w + o); o += (size_t)(n + 1) * 4;
    o = (o + 63) & ~(size_t)63;
    float* dis = (float*)(w + o); o += (size_t)n * 4;
    o = (o + 63) & ~(size_t)63;
    int* ssrc = (int*)(w + o);

    // build CSR (graph is identical across the 3 layers)
    hipMemsetAsync(cnt, 0, (size_t)n * 8, stream);      // cnt + fill
    hist_kernel<<<(E + 255) / 256, 256, 0, stream>>>(col, cnt, E);
    scan_kernel<<<1, 1024, 0, stream>>>(cnt, ptrv, n);
    dis_kernel<<<(n + 255) / 256, 256, 0, stream>>>(cnt, dis, n);
    scatter_kernel<<<(E + 255) / 256, 256, 0, stream>>>(row, col, ptrv, fill, ssrc, E);

    const float* Ws[3] = {W0, W1, W2};
    const float* bs[3] = {b0, b1, b2};
    const float* act = x;
    for (int l = 0; l < 3; ++l) {
        gemm128<<<(n + GBM - 1) / GBM, 256, 0, stream>>>(act, Ws[l], hbuf, n);
        agg_kernel<<<(n + 3) / 4, 256, 0, stream>>>(hbuf, ptrv, ssrc, dis, bs[l], out, n);
        act = out;   // d_out doubles as the activation ping buffer
    }
}

// Round 2
// 391.694 us; speedup vs baseline: 1.1235x; 1.1235x over previous
//
#include <hip/hip_runtime.h>
#include <hip/hip_bf16.h>

#define D 128          // feature dim (D_IN == D_H == 128)
#define TBM 128        // GEMM row tile
#define TBK 32         // GEMM k tile
#define SA_STRIDE 36   // padded k-stride for A tile (float4-aligned)

// ---------------- CSR build ----------------

__global__ void hist_kernel(const int* __restrict__ col, int* __restrict__ cnt, int E) {
    int i = blockIdx.x * 256 + threadIdx.x;
    if (i < E) atomicAdd(&cnt[col[i]], 1);
}

// pass 1: per-block sums of 256 counts
__global__ __launch_bounds__(256) void scan_part1(const int* __restrict__ cnt,
                                                  int* __restrict__ bsum, int n) {
    __shared__ int ws[4];
    const int tid = threadIdx.x;
    const int i = blockIdx.x * 256 + tid;
    int v = (i < n) ? cnt[i] : 0;
    #pragma unroll
    for (int off = 32; off > 0; off >>= 1) v += __shfl_down(v, off, 64);
    if ((tid & 63) == 0) ws[tid >> 6] = v;
    __syncthreads();
    if (tid == 0) bsum[blockIdx.x] = ws[0] + ws[1] + ws[2] + ws[3];
}

// pass 2: single block scans the <=256 block sums -> exclusive prefixes + total
__global__ __launch_bounds__(256) void scan_part2(const int* __restrict__ bsum,
                                                  int* __restrict__ bpre,
                                                  int* __restrict__ total_out, int nb) {
    __shared__ int ws[4];
    const int tid = threadIdx.x;
    const int lane = tid & 63;
    const int wid = tid >> 6;
    int v = (tid < nb) ? bsum[tid] : 0;
    int x = v;
    #pragma unroll
    for (int off = 1; off < 64; off <<= 1) {
        int y = __shfl_up(x, off, 64);
        if (lane >= off) x += y;
    }
    if (lane == 63) ws[wid] = x;
    __syncthreads();
    int wpre = 0;
    #pragma unroll
    for (int w = 0; w < 4; ++w) if (w < wid) wpre += ws[w];
    int inc = wpre + x;
    if (tid < nb) bpre[tid] = inc - v;      // exclusive
    if (tid == 255) *total_out = inc;       // total (tail values are 0)
}

// pass 3: intra-block exclusive scan + block prefix -> ptr
__global__ __launch_bounds__(256) void scan_part3(const int* __restrict__ cnt,
                                                  const int* __restrict__ bpre,
                                                  int* __restrict__ ptr, int n) {
    __shared__ int ws[4];
    const int tid = threadIdx.x;
    const int lane = tid & 63;
    const int wid = tid >> 6;
    const int i = blockIdx.x * 256 + tid;
    int v = (i < n) ? cnt[i] : 0;
    int x = v;
    #pragma unroll
    for (int off = 1; off < 64; off <<= 1) {
        int y = __shfl_up(x, off, 64);
        if (lane >= off) x += y;
    }
    if (lane == 63) ws[wid] = x;
    __syncthreads();
    int wpre = 0;
    #pragma unroll
    for (int w = 0; w < 4; ++w) if (w < wid) wpre += ws[w];
    if (i < n) ptr[i] = bpre[blockIdx.x] + wpre + x - v;   // exclusive
}

__global__ void dis_kernel(const int* __restrict__ cnt, float* __restrict__ dis, int n) {
    int i = blockIdx.x * 256 + threadIdx.x;
    if (i < n) dis[i] = rsqrtf((float)(cnt[i] + 1));   // +1 = self-loop
}

__global__ void scatter_kernel(const int* __restrict__ row, const int* __restrict__ col,
                               const int* __restrict__ ptr, int* __restrict__ fill,
                               int* __restrict__ ssrc, int E) {
    int i = blockIdx.x * 256 + threadIdx.x;
    if (i < E) {
        int d = col[i];
        int p = ptr[d] + atomicAdd(&fill[d], 1);
        ssrc[p] = row[i];
    }
}

// ---------------- GEMM: C[r] = dis[r] * (A @ W)[r], fp32, 128x128 tile ----------------

__global__ __launch_bounds__(256) void gemm128(const float* __restrict__ A,
                                               const float* __restrict__ Wm,
                                               const float* __restrict__ dis,
                                               float* __restrict__ C, int M) {
    __shared__ float sA[TBM * SA_STRIDE];   // 18432 B
    __shared__ float sW[TBK * D];           // 16384 B
    const int tid  = threadIdx.x;
    const int row0 = blockIdx.x * TBM;
    const int tx = tid & 15;                // col group: 8 cols
    const int ty = tid >> 4;                // row group: 8 rows
    const int c0 = tx * 8;
    const int r0 = ty * 8;

    float acc[8][8];
    #pragma unroll
    for (int r = 0; r < 8; ++r)
        #pragma unroll
        for (int c = 0; c < 8; ++c) acc[r][c] = 0.f;

    const int lr = tid >> 3;          // A-load row   0..31 (x4 iters)
    const int lk = (tid & 7) * 4;     // A-load k     0..28
    const int wr = tid >> 5;          // W-load k     0..7 (x4 iters)
    const int wc = (tid & 31) * 4;    // W-load col   0..124

    for (int k0 = 0; k0 < D; k0 += TBK) {
        #pragma unroll
        for (int rr = 0; rr < TBM; rr += 32) {
            int r = lr + rr;
            int grow = row0 + r;
            if (grow >= M) grow = M - 1;
            *(float4*)&sA[r * SA_STRIDE + lk] = *(const float4*)&A[(size_t)grow * D + k0 + lk];
        }
        #pragma unroll
        for (int kk = 0; kk < TBK; kk += 8) {
            int k = wr + kk;
            *(float4*)&sW[k * D + wc] = *(const float4*)&Wm[(size_t)(k0 + k) * D + wc];
        }
        __syncthreads();
        #pragma unroll
        for (int k = 0; k < TBK; k += 4) {
            float4 a[8];
            #pragma unroll
            for (int r = 0; r < 8; ++r)
                a[r] = *(float4*)&sA[(r0 + r) * SA_STRIDE + k];
            #pragma unroll
            for (int kk = 0; kk < 4; ++kk) {
                float4 w0 = *(float4*)&sW[(k + kk) * D + c0];
                float4 w1 = *(float4*)&sW[(k + kk) * D + c0 + 4];
                #pragma unroll
                for (int r = 0; r < 8; ++r) {
                    float av = (kk == 0) ? a[r].x : (kk == 1) ? a[r].y
                             : (kk == 2) ? a[r].z : a[r].w;
                    acc[r][0] += av * w0.x; acc[r][1] += av * w0.y;
                    acc[r][2] += av * w0.z; acc[r][3] += av * w0.w;
                    acc[r][4] += av * w1.x; acc[r][5] += av * w1.y;
                    acc[r][6] += av * w1.z; acc[r][7] += av * w1.w;
                }
            }
        }
        __syncthreads();
    }
    #pragma unroll
    for (int r = 0; r < 8; ++r) {
        int grow = row0 + r0 + r;
        if (grow < M) {
            float dv = dis[grow];
            float4 o0 = {acc[r][0]*dv, acc[r][1]*dv, acc[r][2]*dv, acc[r][3]*dv};
            float4 o1 = {acc[r][4]*dv, acc[r][5]*dv, acc[r][6]*dv, acc[r][7]*dv};
            *(float4*)&C[(size_t)grow * D + c0]     = o0;
            *(float4*)&C[(size_t)grow * D + c0 + 4] = o1;
        }
    }
}

// ---------------- Aggregation: one wave per node, pure gather-sum ----------------
// H is pre-scaled by dis[row]:  out[v] = relu( dis[v] * (H[v] + sum_e H[src_e]) + b )

__global__ __launch_bounds__(256) void agg_kernel(const float* __restrict__ H,
                                                  const int* __restrict__ ptr,
                                                  const int* __restrict__ ssrc,
                                                  const float* __restrict__ dis,
                                                  const float* __restrict__ bias,
                                                  float* __restrict__ out, int n) {
    const int v    = (blockIdx.x * 256 + threadIdx.x) >> 6;
    const int lane = threadIdx.x & 63;
    if (v >= n) return;
    const int fo = lane * 2;

    float2 hv = *(const float2*)&H[(size_t)v * D + fo];
    float ax = hv.x, ay = hv.y;

    const int e0 = ptr[v], e1 = ptr[v + 1];
    int e = e0;
    for (; e + 4 <= e1; e += 4) {
        int s0 = ssrc[e], s1 = ssrc[e + 1], s2 = ssrc[e + 2], s3 = ssrc[e + 3];
        float2 h0 = *(const float2*)&H[(size_t)s0 * D + fo];
        float2 h1 = *(const float2*)&H[(size_t)s1 * D + fo];
        float2 h2 = *(const float2*)&H[(size_t)s2 * D + fo];
        float2 h3 = *(const float2*)&H[(size_t)s3 * D + fo];
        ax += h0.x + h1.x + h2.x + h3.x;
        ay += h0.y + h1.y + h2.y + h3.y;
    }
    for (; e < e1; ++e) {
        int s = ssrc[e];
        float2 h = *(const float2*)&H[(size_t)s * D + fo];
        ax += h.x;
        ay += h.y;
    }
    const float dv = dis[v];
    float2 bb = *(const float2*)&bias[fo];
    float2 res;
    res.x = fmaxf(fmaf(dv, ax, bb.x), 0.f);
    res.y = fmaxf(fmaf(dv, ay, bb.y), 0.f);
    *(float2*)&out[(size_t)v * D + fo] = res;
}

// ---------------- launch ----------------

extern "C" void kernel_launch(void* const* d_in, const int* in_sizes, int n_in,
                              void* d_out, int out_size, void* d_ws, size_t ws_size,
                              hipStream_t stream) {
    const float* x  = (const float*)d_in[0];
    const int*   ei = (const int*)d_in[1];
    const float* W0 = (const float*)d_in[2];
    const float* b0 = (const float*)d_in[3];
    const float* W1 = (const float*)d_in[4];
    const float* b1 = (const float*)d_in[5];
    const float* W2 = (const float*)d_in[6];
    const float* b2 = (const float*)d_in[7];
    float* out = (float*)d_out;

    const int n = in_sizes[0] / D;     // 50000
    const int E = in_sizes[1] / 2;     // 640000
    const int* row = ei;
    const int* col = ei + E;
    const int nb = (n + 255) / 256;    // scan blocks (196)

    char* w = (char*)d_ws;
    float* hbuf = (float*)w;
    size_t o = (size_t)n * D * 4;
    int* cnt  = (int*)(w + o); o += (size_t)n * 4;
    int* fill = (int*)(w + o); o += (size_t)n * 4;      // adjacent to cnt -> one memset
    int* ptrv = (int*)(w + o); o += (size_t)(n + 1) * 4;
    o = (o + 63) & ~(size_t)63;
    float* dis = (float*)(w + o); o += (size_t)n * 4;
    o = (o + 63) & ~(size_t)63;
    int* bsum = (int*)(w + o); o += 256 * 4;
    int* bpre = (int*)(w + o); o += 256 * 4;
    o = (o + 63) & ~(size_t)63;
    int* ssrc = (int*)(w + o);

    // build CSR (graph is identical across the 3 layers)
    hipMemsetAsync(cnt, 0, (size_t)n * 8, stream);      // cnt + fill
    hist_kernel<<<(E + 255) / 256, 256, 0, stream>>>(col, cnt, E);
    scan_part1<<<nb, 256, 0, stream>>>(cnt, bsum, n);
    scan_part2<<<1, 256, 0, stream>>>(bsum, bpre, ptrv + n, nb);
    scan_part3<<<nb, 256, 0, stream>>>(cnt, bpre, ptrv, n);
    dis_kernel<<<(n + 255) / 256, 256, 0, stream>>>(cnt, dis, n);
    scatter_kernel<<<(E + 255) / 256, 256, 0, stream>>>(row, col, ptrv, fill, ssrc, E);

    const float* Ws[3] = {W0, W1, W2};
    const float* bs[3] = {b0, b1, b2};
    const float* act = x;
    for (int l = 0; l < 3; ++l) {
        gemm128<<<(n + TBM - 1) / TBM, 256, 0, stream>>>(act, Ws[l], dis, hbuf, n);
        agg_kernel<<<(n + 3) / 4, 256, 0, stream>>>(hbuf, ptrv, ssrc, dis, bs[l], out, n);
        act = out;   // d_out doubles as the activation ping buffer
    }
}

// Round 3
// 291.513 us; speedup vs baseline: 1.5096x; 1.3437x over previous
//
#include <hip/hip_runtime.h>
#include <hip/hip_bf16.h>

#define D 128
typedef _Float16 f16;
typedef f16 f16x8 __attribute__((ext_vector_type(8)));
typedef f16 f16x2 __attribute__((ext_vector_type(2)));
typedef float f32x4 __attribute__((ext_vector_type(4)));

// ---------------- CSR build ----------------

__global__ void hist_kernel(const int* __restrict__ col, int* __restrict__ cnt, int E) {
    int i = blockIdx.x * 256 + threadIdx.x;
    if (i < E) atomicAdd(&cnt[col[i]], 1);
}

__global__ __launch_bounds__(256) void scan_part1(const int* __restrict__ cnt,
                                                  int* __restrict__ bsum, int n) {
    __shared__ int ws[4];
    const int tid = threadIdx.x;
    const int i = blockIdx.x * 256 + tid;
    int v = (i < n) ? cnt[i] : 0;
    #pragma unroll
    for (int off = 32; off > 0; off >>= 1) v += __shfl_down(v, off, 64);
    if ((tid & 63) == 0) ws[tid >> 6] = v;
    __syncthreads();
    if (tid == 0) bsum[blockIdx.x] = ws[0] + ws[1] + ws[2] + ws[3];
}

__global__ __launch_bounds__(256) void scan_part2(const int* __restrict__ bsum,
                                                  int* __restrict__ bpre,
                                                  int* __restrict__ total_out, int nb) {
    __shared__ int ws[4];
    const int tid = threadIdx.x;
    const int lane = tid & 63;
    const int wid = tid >> 6;
    int v = (tid < nb) ? bsum[tid] : 0;
    int x = v;
    #pragma unroll
    for (int off = 1; off < 64; off <<= 1) {
        int y = __shfl_up(x, off, 64);
        if (lane >= off) x += y;
    }
    if (lane == 63) ws[wid] = x;
    __syncthreads();
    int wpre = 0;
    #pragma unroll
    for (int w = 0; w < 4; ++w) if (w < wid) wpre += ws[w];
    int inc = wpre + x;
    if (tid < nb) bpre[tid] = inc - v;
    if (tid == 255) *total_out = inc;
}

__global__ __launch_bounds__(256) void scan_part3(const int* __restrict__ cnt,
                                                  const int* __restrict__ bpre,
                                                  int* __restrict__ ptr, int n) {
    __shared__ int ws[4];
    const int tid = threadIdx.x;
    const int lane = tid & 63;
    const int wid = tid >> 6;
    const int i = blockIdx.x * 256 + tid;
    int v = (i < n) ? cnt[i] : 0;
    int x = v;
    #pragma unroll
    for (int off = 1; off < 64; off <<= 1) {
        int y = __shfl_up(x, off, 64);
        if (lane >= off) x += y;
    }
    if (lane == 63) ws[wid] = x;
    __syncthreads();
    int wpre = 0;
    #pragma unroll
    for (int w = 0; w < 4; ++w) if (w < wid) wpre += ws[w];
    if (i < n) ptr[i] = bpre[blockIdx.x] + wpre + x - v;
}

// dis padded to n_pad; entries >= n set to 0 (never used for live rows)
__global__ void dis_kernel(const int* __restrict__ cnt, float* __restrict__ dis,
                           int n, int n_pad) {
    int i = blockIdx.x * 256 + threadIdx.x;
    if (i < n_pad) dis[i] = (i < n) ? rsqrtf((float)(cnt[i] + 1)) : 0.f;
}

__global__ void scatter_kernel(const int* __restrict__ row, const int* __restrict__ col,
                               const int* __restrict__ ptr, int* __restrict__ fill,
                               int* __restrict__ ssrc, int E) {
    int i = blockIdx.x * 256 + threadIdx.x;
    if (i < E) {
        int d = col[i];
        int p = ptr[d] + atomicAdd(&fill[d], 1);
        ssrc[p] = row[i];
    }
}

// ---------------- W transpose+convert: WT_l[n][k] = (f16) W_l[k][n] ----------------

__global__ void cvtW_kernel(const float* __restrict__ W0, const float* __restrict__ W1,
                            const float* __restrict__ W2, f16* __restrict__ WT) {
    int id = blockIdx.x * 256 + threadIdx.x;        // 3*16384 total
    int l = id >> 14;
    int e = id & 16383;
    int k = e >> 7, nn = e & 127;
    const float* W = (l == 0) ? W0 : (l == 1) ? W1 : W2;
    WT[(size_t)l * 16384 + nn * 128 + k] = (f16)W[k * 128 + nn];
}

// ---------------- MFMA fp16 GEMM: H[r] = (f16)( dis[r] * (A @ W)[r] ) ----------------
// 64-row tile, 256 threads (4 waves), full K=N=128 per block.
// LDS swizzle: 16B unit (r,b) stored at unit index r*16 + (b ^ (r&15)).

template <bool A_F32>
__global__ __launch_bounds__(256) void gemm_mfma(const void* __restrict__ Aptr,
                                                 const f16* __restrict__ WT,
                                                 const float* __restrict__ dis,
                                                 f16* __restrict__ H, int n) {
    __shared__ f16 sA[64 * 128];    // 16 KB
    __shared__ f16 sW[128 * 128];   // 32 KB
    const int tid = threadIdx.x;
    const int row0 = blockIdx.x * 64;

    // stage A: 1024 units of 16B
    #pragma unroll
    for (int i = 0; i < 4; ++i) {
        int f = i * 256 + tid;
        int r = f >> 4, b = f & 15;
        int grow = row0 + r; if (grow >= n) grow = n - 1;
        int u = (r << 4) | (b ^ (r & 15));
        if (A_F32) {
            const float* src = (const float*)Aptr + (size_t)grow * D + b * 8;
            float4 x0 = *(const float4*)src;
            float4 x1 = *(const float4*)(src + 4);
            f16x8 h;
            h[0] = (f16)x0.x; h[1] = (f16)x0.y; h[2] = (f16)x0.z; h[3] = (f16)x0.w;
            h[4] = (f16)x1.x; h[5] = (f16)x1.y; h[6] = (f16)x1.z; h[7] = (f16)x1.w;
            *(f16x8*)&sA[u * 8] = h;
        } else {
            const f16* src = (const f16*)Aptr + (size_t)grow * D + b * 8;
            *(f16x8*)&sA[u * 8] = *(const f16x8*)src;
        }
    }
    // stage WT: 2048 units
    #pragma unroll
    for (int i = 0; i < 8; ++i) {
        int f = i * 256 + tid;
        int r = f >> 4, b = f & 15;
        int u = (r << 4) | (b ^ (r & 15));
        *(f16x8*)&sW[u * 8] = *(const f16x8*)&WT[(size_t)r * D + b * 8];
    }
    __syncthreads();

    const int w = tid >> 6, lane = tid & 63;
    const int q = lane >> 4, c = lane & 15;

    f16x8 afr[4];
    #pragma unroll
    for (int t = 0; t < 4; ++t) {
        int r = w * 16 + c;
        int b = t * 4 + q;
        afr[t] = *(const f16x8*)&sA[(((r << 4) | (b ^ c))) * 8];
    }

    f32x4 acc[8];
    #pragma unroll
    for (int nt = 0; nt < 8; ++nt) acc[nt] = (f32x4)0.f;

    #pragma unroll
    for (int nt = 0; nt < 8; ++nt) {
        #pragma unroll
        for (int t = 0; t < 4; ++t) {
            int rn = nt * 16 + c;
            int b = t * 4 + q;
            f16x8 bfr = *(const f16x8*)&sW[(((rn << 4) | (b ^ c))) * 8];
            acc[nt] = __builtin_amdgcn_mfma_f32_16x16x32_f16(afr[t], bfr, acc[nt], 0, 0, 0);
        }
    }

    // epilogue: C/D layout col=lane&15, row=quad*4+reg
    const int rbase = row0 + w * 16 + q * 4;
    float4 dv4 = *(const float4*)&dis[rbase];   // dis padded to n_pad, 16B aligned
    #pragma unroll
    for (int reg = 0; reg < 4; ++reg) {
        int grow = rbase + reg;
        if (grow < n) {
            float dv = (reg == 0) ? dv4.x : (reg == 1) ? dv4.y : (reg == 2) ? dv4.z : dv4.w;
            #pragma unroll
            for (int nt = 0; nt < 8; ++nt)
                H[(size_t)grow * D + nt * 16 + c] = (f16)(acc[nt][reg] * dv);
        }
    }
}

// ---------------- Aggregation: one wave per node, fp16 gather ----------------
// H pre-scaled by dis[src]:  y[v] = relu( dis[v] * (H[v] + sum_e H[src_e]) + b )
// LAST=false: write fp16 act (next layer's A);  LAST=true: write fp32 d_out.

template <bool LAST>
__global__ __launch_bounds__(256) void agg_kernel(const f16* __restrict__ H,
                                                  const int* __restrict__ ptr,
                                                  const int* __restrict__ ssrc,
                                                  const float* __restrict__ dis,
                                                  const float* __restrict__ bias,
                                                  float* __restrict__ out,
                                                  f16* __restrict__ act, int n) {
    const int v    = (blockIdx.x * 256 + threadIdx.x) >> 6;
    const int lane = threadIdx.x & 63;
    if (v >= n) return;
    const int fo = lane * 2;

    f16x2 hv = *(const f16x2*)&H[(size_t)v * D + fo];
    float ax = (float)hv[0], ay = (float)hv[1];

    const int e0 = ptr[v], e1 = ptr[v + 1];
    int e = e0;
    for (; e + 4 <= e1; e += 4) {
        int s0 = ssrc[e], s1 = ssrc[e + 1], s2 = ssrc[e + 2], s3 = ssrc[e + 3];
        f16x2 h0 = *(const f16x2*)&H[(size_t)s0 * D + fo];
        f16x2 h1 = *(const f16x2*)&H[(size_t)s1 * D + fo];
        f16x2 h2 = *(const f16x2*)&H[(size_t)s2 * D + fo];
        f16x2 h3 = *(const f16x2*)&H[(size_t)s3 * D + fo];
        ax += (float)h0[0] + (float)h1[0] + (float)h2[0] + (float)h3[0];
        ay += (float)h0[1] + (float)h1[1] + (float)h2[1] + (float)h3[1];
    }
    for (; e < e1; ++e) {
        int s = ssrc[e];
        f16x2 h = *(const f16x2*)&H[(size_t)s * D + fo];
        ax += (float)h[0];
        ay += (float)h[1];
    }
    const float dv = dis[v];
    float2 bb = *(const float2*)&bias[fo];
    float rx = fmaxf(fmaf(dv, ax, bb.x), 0.f);
    float ry = fmaxf(fmaf(dv, ay, bb.y), 0.f);
    if (LAST) {
        float2 res = {rx, ry};
        *(float2*)&out[(size_t)v * D + fo] = res;
    } else {
        f16x2 res;
        res[0] = (f16)rx; res[1] = (f16)ry;
        *(f16x2*)&act[(size_t)v * D + fo] = res;
    }
}

// ---------------- launch ----------------

extern "C" void kernel_launch(void* const* d_in, const int* in_sizes, int n_in,
                              void* d_out, int out_size, void* d_ws, size_t ws_size,
                              hipStream_t stream) {
    const float* x  = (const float*)d_in[0];
    const int*   ei = (const int*)d_in[1];
    const float* W0 = (const float*)d_in[2];
    const float* b0 = (const float*)d_in[3];
    const float* W1 = (const float*)d_in[4];
    const float* b1 = (const float*)d_in[5];
    const float* W2 = (const float*)d_in[6];
    const float* b2 = (const float*)d_in[7];
    float* out = (float*)d_out;

    const int n = in_sizes[0] / D;          // 50000
    const int E = in_sizes[1] / 2;          // 640000
    const int n_pad = (n + 63) & ~63;       // 50048
    const int* row = ei;
    const int* col = ei + E;
    const int nb = (n + 255) / 256;

    char* w = (char*)d_ws;
    size_t o = 0;
    f16* hbuf = (f16*)(w + o); o += (size_t)n_pad * D * 2;
    f16* act  = (f16*)(w + o); o += (size_t)n_pad * D * 2;
    f16* WT   = (f16*)(w + o); o += (size_t)3 * 16384 * 2;
    o = (o + 63) & ~(size_t)63;
    int* cnt  = (int*)(w + o); o += (size_t)n * 4;
    int* fill = (int*)(w + o); o += (size_t)n * 4;   // adjacent to cnt -> one memset
    int* ptrv = (int*)(w + o); o += (size_t)(n + 1) * 4;
    o = (o + 63) & ~(size_t)63;
    float* dis = (float*)(w + o); o += (size_t)n_pad * 4;
    int* bsum = (int*)(w + o); o += 256 * 4;
    int* bpre = (int*)(w + o); o += 256 * 4;
    o = (o + 63) & ~(size_t)63;
    int* ssrc = (int*)(w + o);

    // CSR build (graph identical across layers)
    hipMemsetAsync(cnt, 0, (size_t)n * 8, stream);
    hist_kernel<<<(E + 255) / 256, 256, 0, stream>>>(col, cnt, E);
    scan_part1<<<nb, 256, 0, stream>>>(cnt, bsum, n);
    scan_part2<<<1, 256, 0, stream>>>(bsum, bpre, ptrv + n, nb);
    scan_part3<<<nb, 256, 0, stream>>>(cnt, bpre, ptrv, n);
    dis_kernel<<<(n_pad + 255) / 256, 256, 0, stream>>>(cnt, dis, n, n_pad);
    scatter_kernel<<<(E + 255) / 256, 256, 0, stream>>>(row, col, ptrv, fill, ssrc, E);
    cvtW_kernel<<<192, 256, 0, stream>>>(W0, W1, W2, WT);

    const float* bs[3] = {b0, b1, b2};
    const int gblocks = (n + 63) / 64;
    const int ablocks = (n + 3) / 4;

    // layer 0: A = x (fp32)
    gemm_mfma<true><<<gblocks, 256, 0, stream>>>(x, WT, dis, hbuf, n);
    agg_kernel<false><<<ablocks, 256, 0, stream>>>(hbuf, ptrv, ssrc, dis, bs[0], out, act, n);
    // layer 1
    gemm_mfma<false><<<gblocks, 256, 0, stream>>>(act, WT + 16384, dis, hbuf, n);
    agg_kernel<false><<<ablocks, 256, 0, stream>>>(hbuf, ptrv, ssrc, dis, bs[1], out, act, n);
    // layer 2 -> fp32 d_out
    gemm_mfma<false><<<gblocks, 256, 0, stream>>>(act, WT + 2 * 16384, dis, hbuf, n);
    agg_kernel<true><<<ablocks, 256, 0, stream>>>(hbuf, ptrv, ssrc, dis, bs[2], out, act, n);
}